// Round 12
// baseline (1332.699 us; speedup 1.0000x reference)
//
#include <hip/hip_runtime.h>
#include <hip/hip_bf16.h>

// RNNClassifier: B=64, T=2048, V=50000, E=256, H=256, O=16
// R11: two launches only.
// K1 (MFMA f16): xh16[B*T][H] = fp16( emb[x] @ W_ih^T + b_ih + b_hh ).
//   R8-proven 64-row tile; W_ih read as fp32 with inline convert in the
//   fragment build (2x float4 per frag; 256KB table, L2-resident) -> k0
//   and the Wih16 intermediate are deleted (one fewer launch + gap).
// K2 (MFMA f16): scan -- byte-identical to the 5x-verified local optimum
//   (k2=1155-1158us across R5/R8/R10; 16 WGs x 4 chains x 16 waves,
//   4 waves/SIMD). W_hh LDS-staged from fp32 (R4 fix: defeats the
//   const-pointer remat that re-streamed weights from L2 every step).
//   One barrier/step; two 4-deep MFMA chains (R6 tree, R7 reorder,
//   R9 fusion, R1/R2/R3 occupancy/pinning attacks all regressed or null).
//   Step = 1354 cyc: 512 matrix-issue invariant (128 MFMA/WG/step over
//   4 SIMDs) + ~840 barrier/read-latency/tanh tail, attack-resistant.
//   HP=272 keeps the 4-chain x 4-quad b128 reads 2-way banked (free).

#define B_  64
#define T_  2048
#define E_  256
#define H_  256
#define O_  16
#define H2_ 128
#define CH  4     // chains per WG
#define HP  272   // padded h stride (halves): 136 dwords ≡ 8 (mod 32)

typedef _Float16 f16x2 __attribute__((ext_vector_type(2)));
typedef _Float16 f16x4 __attribute__((ext_vector_type(4)));
typedef _Float16 f16x8 __attribute__((ext_vector_type(8)));
typedef float    f32x4 __attribute__((ext_vector_type(4)));

// Barrier without __syncthreads()'s vmcnt(0) drain. Safe: in-loop cross-wave
// communication is LDS-only.
#define LDS_BARRIER() asm volatile("s_waitcnt lgkmcnt(0)\n\ts_barrier" ::: "memory")

__device__ __forceinline__ float tanh_fast(float x) {
  const float e = __expf(2.0f * x);
  return fmaf(-2.0f, __builtin_amdgcn_rcpf(e + 1.0f), 1.0f);
}

__device__ __forceinline__ f32x4 cvt4(f16x4 v) {
  return (f32x4){(float)v[0], (float)v[1], (float)v[2], (float)v[3]};
}

// ---------------------------------------------------------------------------
// K1: gathered GEMM via MFMA (R8 64-row tile; W_ih fp32 inline-converted).
// ---------------------------------------------------------------------------
__global__ __launch_bounds__(256) void k1_xh(
    const int* __restrict__ x, const float* __restrict__ emb,
    const float* __restrict__ W_ih, const float* __restrict__ b_ih,
    const float* __restrict__ b_hh, _Float16* __restrict__ xh) {
  __shared__ _Float16 A16[64][264];
  const int tid  = threadIdx.x;
  const int w    = tid >> 6;
  const int lane = tid & 63;
  const int nl   = lane & 15;
  const int koff = (lane >> 4) << 3;
  const long r0  = (long)blockIdx.x * 64;

  {
    const int c4 = lane << 2;
#pragma unroll
    for (int it = 0; it < 16; ++it) {
      const int row = (it << 2) + w;
      const long tok = x[r0 + row];
      const float4 v = *(const float4*)&emb[tok * E_ + c4];
      f16x4 hv;
      hv[0] = (_Float16)v.x; hv[1] = (_Float16)v.y;
      hv[2] = (_Float16)v.z; hv[3] = (_Float16)v.w;
      *(f16x4*)&A16[row][c4] = hv;
    }
  }

  // B-fragments straight from fp32 W_ih (inline convert; L2-resident).
  f16x8 bfr[4][8];
#pragma unroll
  for (int nt = 0; nt < 4; ++nt) {
    const int n = (w << 6) + (nt << 4) + nl;
#pragma unroll
    for (int kt = 0; kt < 8; ++kt) {
      const float4 lo = *(const float4*)&W_ih[n * E_ + (kt << 5) + koff];
      const float4 hi = *(const float4*)&W_ih[n * E_ + (kt << 5) + koff + 4];
      f16x8 v;
      v[0] = (_Float16)lo.x; v[1] = (_Float16)lo.y;
      v[2] = (_Float16)lo.z; v[3] = (_Float16)lo.w;
      v[4] = (_Float16)hi.x; v[5] = (_Float16)hi.y;
      v[6] = (_Float16)hi.z; v[7] = (_Float16)hi.w;
      bfr[nt][kt] = v;
    }
  }
  __syncthreads();

  f32x4 acc[4][4];
#pragma unroll
  for (int mt = 0; mt < 4; ++mt)
#pragma unroll
    for (int nt = 0; nt < 4; ++nt) acc[mt][nt] = (f32x4){};

#pragma unroll
  for (int mt = 0; mt < 4; ++mt) {
#pragma unroll
    for (int kt = 0; kt < 8; ++kt) {
      const f16x8 a = *(const f16x8*)&A16[(mt << 4) + nl][(kt << 5) + koff];
#pragma unroll
      for (int nt = 0; nt < 4; ++nt)
        acc[mt][nt] = __builtin_amdgcn_mfma_f32_16x16x32_f16(a, bfr[nt][kt], acc[mt][nt], 0, 0, 0);
    }
  }
  __syncthreads();

  {
    const int rsub = (lane >> 4) << 2;
#pragma unroll
    for (int nt = 0; nt < 4; ++nt) {
      const int n = (w << 6) + (nt << 4) + nl;
      const float bias = b_ih[n] + b_hh[n];
#pragma unroll
      for (int mt = 0; mt < 4; ++mt)
#pragma unroll
        for (int j = 0; j < 4; ++j)
          A16[(mt << 4) + rsub + j][n] = (_Float16)(acc[mt][nt][j] + bias);
    }
  }
  __syncthreads();

  {
#pragma unroll
    for (int i = 0; i < 8; ++i) {
      const int row = (w << 4) + (i << 1) + (lane >> 5);
      const int col = (lane & 31) << 3;
      *(f16x8*)&xh[(r0 + row) * H_ + col] = *(const f16x8*)&A16[row][col];
    }
  }
}

// ---------------------------------------------------------------------------
// K2: 16-wave scan, 16 WGs x 1024 thr (4 waves/SIMD). Wave w owns rows
// [16w,16w+16) (one m-tile). Lane (quad,nl): B col nl (chain cc=nl&3,
// copy g=nl>>2), k-slice koff=quad*8. After MFMA, lane holds C rows
// quad*4+j (j=0..3) of col nl; copy-group g finishes row j=g: 1 tanh,
// 1 scalar f16 write. Per body: 8 ds_read b128 (4x broadcast) -> two
// 4-deep MFMA chains (C_in = cvt4(xq) on chain 0) -> 1 add -> 3 cndmask
// -> tanh -> write -> LDS_BARRIER. One barrier per step. EXACT R8 body.
// ---------------------------------------------------------------------------
__global__ __attribute__((amdgpu_flat_work_group_size(1024, 1024)))
__attribute__((amdgpu_waves_per_eu(4, 4))) void k2_rnn(
    const _Float16* __restrict__ xh, const float* __restrict__ W_hh,
    const float* __restrict__ fc1_w, const float* __restrict__ fc1_b,
    const float* __restrict__ fc2_w, const float* __restrict__ fc2_b,
    float* __restrict__ out) {
  __shared__ _Float16 whh_s[H_ * H_];   // 128 KiB staged W_hh (row-major f16)
  __shared__ _Float16 h16[2][CH][HP];   // ping-pong hidden (fp16)
  __shared__ float    hid_s[CH][H2_ + 4];

  const int tid   = threadIdx.x;
  const int w     = tid >> 6;            // wave 0..15
  const int lane  = tid & 63;
  const int nl    = lane & 15;
  const int quad  = lane >> 4;
  const int cc    = nl & (CH - 1);       // chain (= B col mod 4)
  const int g     = nl >> 2;             // copy group 0..3 -> finishes row j=g
  const int koff  = quad << 3;
  const int wrow  = (w << 4) + (quad << 2);  // C row base of this lane
  const int c0    = blockIdx.x * CH;

  // Stage W_hh into LDS straight from fp32, converting inline (one-time,
  // off the recurrence). 65536 floats / (1024 thr x 4) = 16 rounds.
  {
#pragma unroll
    for (int c = 0; c < 16; ++c) {
      const int idx = ((c << 10) + tid) << 2;
      const float4 v = *(const float4*)&W_hh[idx];
      f16x4 hv;
      hv[0] = (_Float16)v.x; hv[1] = (_Float16)v.y;
      hv[2] = (_Float16)v.z; hv[3] = (_Float16)v.w;
      *(f16x4*)&whh_s[idx] = hv;
    }
  }
  // h0 = 0: zero used region [CH][0..256) of buffer 0 (1024 halves).
  if (tid < 128) *(f16x8*)&h16[0][tid >> 5][(tid & 31) << 3] = (f16x8){};
  __syncthreads();

  // A-frags from LDS: W_hh rows 16w+nl, one m-tile = 32 regs. ds_read
  // results can't be remat'ed past the in-loop "memory"-clobber barriers
  // -> forced register-resident (R4-verified approach).
  f16x8 afr[8];
  {
    const int r = (w << 4) + nl;
#pragma unroll
    for (int kt = 0; kt < 8; ++kt)
      afr[kt] = *(const f16x8*)&whh_s[r * H_ + (kt << 5) + koff];
  }

  // xh stream: chain cc, rows wrow..wrow+3 of each step (C_in of this lane's
  // C fragment). Lanes sharing (cc,quad) duplicate addresses -> dedup.
  const _Float16* xb = xh + (size_t)(c0 + cc) * T_ * H_ + wrow;
  f16x4 xq[4], xn[4];                     // reg-resident relay (proven pattern)
#pragma unroll
  for (int s = 0; s < 4; ++s) xq[s] = *(const f16x4*)&xb[(size_t)s * H_];
#pragma unroll
  for (int s = 0; s < 4; ++s) xn[s] = *(const f16x4*)&xb[(size_t)(4 + s) * H_];

#define BODY(P, S)                                                             \
  {                                                                            \
    f16x8 bfr[8];                                                              \
    _Pragma("unroll")                                                          \
    for (int i = 0; i < 8; ++i)                                                \
      bfr[i] = *(const f16x8*)&h16[P][cc][(i << 5) + koff];                    \
    f32x4 ca = __builtin_amdgcn_mfma_f32_16x16x32_f16(afr[0], bfr[0], cvt4(xq[S]), 0, 0, 0); \
    f32x4 cb = __builtin_amdgcn_mfma_f32_16x16x32_f16(afr[4], bfr[4], (f32x4){}, 0, 0, 0);   \
    _Pragma("unroll")                                                          \
    for (int i = 1; i < 4; ++i) {                                              \
      ca = __builtin_amdgcn_mfma_f32_16x16x32_f16(afr[i], bfr[i], ca, 0, 0, 0);              \
      cb = __builtin_amdgcn_mfma_f32_16x16x32_f16(afr[4 + i], bfr[4 + i], cb, 0, 0, 0);      \
    }                                                                          \
    const f32x4 s4 = ca + cb;                                                  \
    const float u01 = (g & 1) ? s4[1] : s4[0];                                 \
    const float u23 = (g & 1) ? s4[3] : s4[2];                                 \
    const float u   = (g & 2) ? u23 : u01;                                     \
    h16[P ^ 1][cc][wrow + g] = (_Float16)tanh_fast(u);                         \
    LDS_BARRIER();                                                             \
  }

  for (int tt = 0; tt < T_; tt += 4) {
    BODY(0, 0)
    BODY(1, 1)
    BODY(0, 2)
    BODY(1, 3)
    // relay rotate: vmcnt wait lands here, on loads issued 4 bodies ago
#pragma unroll
    for (int s = 0; s < 4; ++s) xq[s] = xn[s];
    const int tn = tt + 8;
#pragma unroll
    for (int s = 0; s < 4; ++s) {
      const size_t ti = (size_t)((tn + s) & (T_ - 1)) * H_;  // wrap; tail unused
      xn[s] = *(const f16x4*)&xb[ti];
    }
  }
#undef BODY

  __syncthreads();  // final h(T) is in h16[0] (last body wrote buf 0)

  // MLP head. fc1: 4 chains x 128 outputs = 512 threads; rest idle.
  if (tid < 512) {
    const int pc = tid >> 7;
    const int o_ = tid & 127;
    float s = fc1_b[o_];
#pragma unroll 8
    for (int k = 0; k < H_; ++k) s += fc1_w[o_ * H_ + k] * (float)h16[0][pc][k];
    hid_s[pc][o_] = fmaxf(s, 0.f);
  }
  __syncthreads();
  if (tid < CH * O_) {
    const int c = tid >> 4, o_ = tid & 15;
    float s = fc2_b[o_];
#pragma unroll 8
    for (int k = 0; k < H2_; ++k) s += fc2_w[o_ * H2_ + k] * hid_s[c][k];
    out[(size_t)(c0 + c) * O_ + o_] = s;
  }
}

extern "C" void kernel_launch(void* const* d_in, const int* in_sizes, int n_in,
                              void* d_out, int out_size, void* d_ws, size_t ws_size,
                              hipStream_t stream) {
  const int*   x     = (const int*)d_in[0];
  const float* emb   = (const float*)d_in[1];
  const float* W_ih  = (const float*)d_in[2];
  const float* W_hh  = (const float*)d_in[3];
  const float* b_ih  = (const float*)d_in[4];
  const float* b_hh  = (const float*)d_in[5];
  const float* fc1_w = (const float*)d_in[6];
  const float* fc1_b = (const float*)d_in[7];
  const float* fc2_w = (const float*)d_in[8];
  const float* fc2_b = (const float*)d_in[9];
  float* outp = (float*)d_out;

  _Float16* xh16 = (_Float16*)d_ws;                     // 64 MiB

  k1_xh<<<dim3(B_ * T_ / 64), dim3(256), 0, stream>>>(x, emb, W_ih, b_ih, b_hh, xh16);
  k2_rnn<<<dim3(B_ / CH), dim3(1024), 0, stream>>>(xh16, W_hh, fc1_w, fc1_b, fc2_w, fc2_b, outp);
}

// Round 13
// 1296.267 us; speedup vs baseline: 1.0281x; 1.0281x over previous
//
#include <hip/hip_runtime.h>
#include <hip/hip_bf16.h>

// RNNClassifier: B=64, T=2048, V=50000, E=256, H=256, O=16
// R12 = exact revert to R8, the best measured configuration (1296.8 us).
// K0: W_ih fp32 -> fp16 once into d_ws.
// K1 (MFMA f16): xh16[B*T][H] = fp16( emb[x] @ W_ih^T + b_ih + b_hh ),
//   64-row tile (R10's 32-row retile and R11's inline-fp32 both regressed).
// K2 (MFMA f16): scan -- 5x-verified local optimum (1155-1158us across
//   R5/R8/R10/R11): 16 WGs x 4 chains x 16 waves (4 waves/SIMD). W_hh
//   LDS-staged from fp32 (R4 fix: defeats the const-pointer remat that
//   re-streamed weights from L2 every step in R1-R3). One barrier/step;
//   two 4-deep MFMA chains (R6 indep-acc tree and R7 reorder/pre-cvt both
//   regressed; R9 producer-consumer fusion regressed). Step = 1354 cyc:
//   512 matrix-issue invariant (128 MFMA/WG/step over 4 SIMDs; replication
//   vs spreading cancels in this one-WG-per-h-vector family) + ~840 cyc
//   barrier/ds_read-latency/tanh tail, resistant to 9 distinct attacks.
//   HP=272 keeps the 4-chain x 4-quad b128 reads 2-way banked (free).

#define B_  64
#define T_  2048
#define E_  256
#define H_  256
#define O_  16
#define H2_ 128
#define CH  4     // chains per WG
#define HP  272   // padded h stride (halves): 136 dwords ≡ 8 (mod 32)

typedef _Float16 f16x2 __attribute__((ext_vector_type(2)));
typedef _Float16 f16x4 __attribute__((ext_vector_type(4)));
typedef _Float16 f16x8 __attribute__((ext_vector_type(8)));
typedef float    f32x4 __attribute__((ext_vector_type(4)));

// Barrier without __syncthreads()'s vmcnt(0) drain. Safe: in-loop cross-wave
// communication is LDS-only.
#define LDS_BARRIER() asm volatile("s_waitcnt lgkmcnt(0)\n\ts_barrier" ::: "memory")

__device__ __forceinline__ float tanh_fast(float x) {
  const float e = __expf(2.0f * x);
  return fmaf(-2.0f, __builtin_amdgcn_rcpf(e + 1.0f), 1.0f);
}

__device__ __forceinline__ f32x4 cvt4(f16x4 v) {
  return (f32x4){(float)v[0], (float)v[1], (float)v[2], (float)v[3]};
}

// ---------------------------------------------------------------------------
// K0: W_ih only (W_hh is converted inside k2's staging).
// ---------------------------------------------------------------------------
__global__ __launch_bounds__(256) void k0_cvt(
    const float* __restrict__ W_ih, _Float16* __restrict__ Wih16) {
  const int i = (blockIdx.x * 256 + threadIdx.x) * 4;
  if (i < H_ * E_) {
    float4 a = *(const float4*)&W_ih[i];
    f16x4 ah;
    ah[0]=(_Float16)a.x; ah[1]=(_Float16)a.y; ah[2]=(_Float16)a.z; ah[3]=(_Float16)a.w;
    *(f16x4*)&Wih16[i] = ah;
  }
}

// ---------------------------------------------------------------------------
// K1: gathered GEMM via MFMA (R8-proven 64-row tile).
// ---------------------------------------------------------------------------
__global__ __launch_bounds__(256) void k1_xh(
    const int* __restrict__ x, const float* __restrict__ emb,
    const _Float16* __restrict__ Wih16, const float* __restrict__ b_ih,
    const float* __restrict__ b_hh, _Float16* __restrict__ xh) {
  __shared__ _Float16 A16[64][264];
  const int tid  = threadIdx.x;
  const int w    = tid >> 6;
  const int lane = tid & 63;
  const int nl   = lane & 15;
  const int koff = (lane >> 4) << 3;
  const long r0  = (long)blockIdx.x * 64;

  {
    const int c4 = lane << 2;
#pragma unroll
    for (int it = 0; it < 16; ++it) {
      const int row = (it << 2) + w;
      const long tok = x[r0 + row];
      const float4 v = *(const float4*)&emb[tok * E_ + c4];
      f16x4 hv;
      hv[0] = (_Float16)v.x; hv[1] = (_Float16)v.y;
      hv[2] = (_Float16)v.z; hv[3] = (_Float16)v.w;
      *(f16x4*)&A16[row][c4] = hv;
    }
  }

  f16x8 bfr[4][8];
#pragma unroll
  for (int nt = 0; nt < 4; ++nt) {
    const int n = (w << 6) + (nt << 4) + nl;
#pragma unroll
    for (int kt = 0; kt < 8; ++kt)
      bfr[nt][kt] = *(const f16x8*)&Wih16[n * E_ + (kt << 5) + koff];
  }
  __syncthreads();

  f32x4 acc[4][4];
#pragma unroll
  for (int mt = 0; mt < 4; ++mt)
#pragma unroll
    for (int nt = 0; nt < 4; ++nt) acc[mt][nt] = (f32x4){};

#pragma unroll
  for (int mt = 0; mt < 4; ++mt) {
#pragma unroll
    for (int kt = 0; kt < 8; ++kt) {
      const f16x8 a = *(const f16x8*)&A16[(mt << 4) + nl][(kt << 5) + koff];
#pragma unroll
      for (int nt = 0; nt < 4; ++nt)
        acc[mt][nt] = __builtin_amdgcn_mfma_f32_16x16x32_f16(a, bfr[nt][kt], acc[mt][nt], 0, 0, 0);
    }
  }
  __syncthreads();

  {
    const int rsub = (lane >> 4) << 2;
#pragma unroll
    for (int nt = 0; nt < 4; ++nt) {
      const int n = (w << 6) + (nt << 4) + nl;
      const float bias = b_ih[n] + b_hh[n];
#pragma unroll
      for (int mt = 0; mt < 4; ++mt)
#pragma unroll
        for (int j = 0; j < 4; ++j)
          A16[(mt << 4) + rsub + j][n] = (_Float16)(acc[mt][nt][j] + bias);
    }
  }
  __syncthreads();

  {
#pragma unroll
    for (int i = 0; i < 8; ++i) {
      const int row = (w << 4) + (i << 1) + (lane >> 5);
      const int col = (lane & 31) << 3;
      *(f16x8*)&xh[(r0 + row) * H_ + col] = *(const f16x8*)&A16[row][col];
    }
  }
}

// ---------------------------------------------------------------------------
// K2: 16-wave scan, 16 WGs x 1024 thr (4 waves/SIMD). Wave w owns rows
// [16w,16w+16) (one m-tile). Lane (quad,nl): B col nl (chain cc=nl&3,
// copy g=nl>>2), k-slice koff=quad*8. After MFMA, lane holds C rows
// quad*4+j (j=0..3) of col nl; copy-group g finishes row j=g: 1 tanh,
// 1 scalar f16 write. Per body: 8 ds_read b128 (4x broadcast) -> two
// 4-deep MFMA chains (C_in = cvt4(xq) on chain 0) -> 1 add -> 3 cndmask
// -> tanh -> write -> LDS_BARRIER. One barrier per step.
// ---------------------------------------------------------------------------
__global__ __attribute__((amdgpu_flat_work_group_size(1024, 1024)))
__attribute__((amdgpu_waves_per_eu(4, 4))) void k2_rnn(
    const _Float16* __restrict__ xh, const float* __restrict__ W_hh,
    const float* __restrict__ fc1_w, const float* __restrict__ fc1_b,
    const float* __restrict__ fc2_w, const float* __restrict__ fc2_b,
    float* __restrict__ out) {
  __shared__ _Float16 whh_s[H_ * H_];   // 128 KiB staged W_hh (row-major f16)
  __shared__ _Float16 h16[2][CH][HP];   // ping-pong hidden (fp16)
  __shared__ float    hid_s[CH][H2_ + 4];

  const int tid   = threadIdx.x;
  const int w     = tid >> 6;            // wave 0..15
  const int lane  = tid & 63;
  const int nl    = lane & 15;
  const int quad  = lane >> 4;
  const int cc    = nl & (CH - 1);       // chain (= B col mod 4)
  const int g     = nl >> 2;             // copy group 0..3 -> finishes row j=g
  const int koff  = quad << 3;
  const int wrow  = (w << 4) + (quad << 2);  // C row base of this lane
  const int c0    = blockIdx.x * CH;

  // Stage W_hh into LDS straight from fp32, converting inline (one-time,
  // off the recurrence). 65536 floats / (1024 thr x 4) = 16 rounds.
  {
#pragma unroll
    for (int c = 0; c < 16; ++c) {
      const int idx = ((c << 10) + tid) << 2;
      const float4 v = *(const float4*)&W_hh[idx];
      f16x4 hv;
      hv[0] = (_Float16)v.x; hv[1] = (_Float16)v.y;
      hv[2] = (_Float16)v.z; hv[3] = (_Float16)v.w;
      *(f16x4*)&whh_s[idx] = hv;
    }
  }
  // h0 = 0: zero used region [CH][0..256) of buffer 0 (1024 halves).
  if (tid < 128) *(f16x8*)&h16[0][tid >> 5][(tid & 31) << 3] = (f16x8){};
  __syncthreads();

  // A-frags from LDS: W_hh rows 16w+nl, one m-tile = 32 regs. ds_read
  // results can't be remat'ed past the in-loop "memory"-clobber barriers
  // -> forced register-resident (R4-verified approach).
  f16x8 afr[8];
  {
    const int r = (w << 4) + nl;
#pragma unroll
    for (int kt = 0; kt < 8; ++kt)
      afr[kt] = *(const f16x8*)&whh_s[r * H_ + (kt << 5) + koff];
  }

  // xh stream: chain cc, rows wrow..wrow+3 of each step (C_in of this lane's
  // C fragment). Lanes sharing (cc,quad) duplicate addresses -> dedup.
  const _Float16* xb = xh + (size_t)(c0 + cc) * T_ * H_ + wrow;
  f16x4 xq[4], xn[4];                     // reg-resident relay (proven pattern)
#pragma unroll
  for (int s = 0; s < 4; ++s) xq[s] = *(const f16x4*)&xb[(size_t)s * H_];
#pragma unroll
  for (int s = 0; s < 4; ++s) xn[s] = *(const f16x4*)&xb[(size_t)(4 + s) * H_];

#define BODY(P, S)                                                             \
  {                                                                            \
    f16x8 bfr[8];                                                              \
    _Pragma("unroll")                                                          \
    for (int i = 0; i < 8; ++i)                                                \
      bfr[i] = *(const f16x8*)&h16[P][cc][(i << 5) + koff];                    \
    f32x4 ca = __builtin_amdgcn_mfma_f32_16x16x32_f16(afr[0], bfr[0], cvt4(xq[S]), 0, 0, 0); \
    f32x4 cb = __builtin_amdgcn_mfma_f32_16x16x32_f16(afr[4], bfr[4], (f32x4){}, 0, 0, 0);   \
    _Pragma("unroll")                                                          \
    for (int i = 1; i < 4; ++i) {                                              \
      ca = __builtin_amdgcn_mfma_f32_16x16x32_f16(afr[i], bfr[i], ca, 0, 0, 0);              \
      cb = __builtin_amdgcn_mfma_f32_16x16x32_f16(afr[4 + i], bfr[4 + i], cb, 0, 0, 0);      \
    }                                                                          \
    const f32x4 s4 = ca + cb;                                                  \
    const float u01 = (g & 1) ? s4[1] : s4[0];                                 \
    const float u23 = (g & 1) ? s4[3] : s4[2];                                 \
    const float u   = (g & 2) ? u23 : u01;                                     \
    h16[P ^ 1][cc][wrow + g] = (_Float16)tanh_fast(u);                         \
    LDS_BARRIER();                                                             \
  }

  for (int tt = 0; tt < T_; tt += 4) {
    BODY(0, 0)
    BODY(1, 1)
    BODY(0, 2)
    BODY(1, 3)
    // relay rotate: vmcnt wait lands here, on loads issued 4 bodies ago
#pragma unroll
    for (int s = 0; s < 4; ++s) xq[s] = xn[s];
    const int tn = tt + 8;
#pragma unroll
    for (int s = 0; s < 4; ++s) {
      const size_t ti = (size_t)((tn + s) & (T_ - 1)) * H_;  // wrap; tail unused
      xn[s] = *(const f16x4*)&xb[ti];
    }
  }
#undef BODY

  __syncthreads();  // final h(T) is in h16[0] (last body wrote buf 0)

  // MLP head. fc1: 4 chains x 128 outputs = 512 threads; rest idle.
  if (tid < 512) {
    const int pc = tid >> 7;
    const int o_ = tid & 127;
    float s = fc1_b[o_];
#pragma unroll 8
    for (int k = 0; k < H_; ++k) s += fc1_w[o_ * H_ + k] * (float)h16[0][pc][k];
    hid_s[pc][o_] = fmaxf(s, 0.f);
  }
  __syncthreads();
  if (tid < CH * O_) {
    const int c = tid >> 4, o_ = tid & 15;
    float s = fc2_b[o_];
#pragma unroll 8
    for (int k = 0; k < H2_; ++k) s += fc2_w[o_ * H2_ + k] * hid_s[c][k];
    out[(size_t)(c0 + c) * O_ + o_] = s;
  }
}

extern "C" void kernel_launch(void* const* d_in, const int* in_sizes, int n_in,
                              void* d_out, int out_size, void* d_ws, size_t ws_size,
                              hipStream_t stream) {
  const int*   x     = (const int*)d_in[0];
  const float* emb   = (const float*)d_in[1];
  const float* W_ih  = (const float*)d_in[2];
  const float* W_hh  = (const float*)d_in[3];
  const float* b_ih  = (const float*)d_in[4];
  const float* b_hh  = (const float*)d_in[5];
  const float* fc1_w = (const float*)d_in[6];
  const float* fc1_b = (const float*)d_in[7];
  const float* fc2_w = (const float*)d_in[8];
  const float* fc2_b = (const float*)d_in[9];
  float* outp = (float*)d_out;

  _Float16* xh16  = (_Float16*)d_ws;                    // 64 MiB
  _Float16* Wih16 = xh16 + (size_t)B_ * T_ * H_;        // 128 KiB

  k0_cvt<<<dim3(H_ * E_ / 1024), dim3(256), 0, stream>>>(W_ih, Wih16);
  k1_xh<<<dim3(B_ * T_ / 64), dim3(256), 0, stream>>>(x, emb, Wih16, b_ih, b_hh, xh16);
  k2_rnn<<<dim3(B_ / CH), dim3(1024), 0, stream>>>(xh16, W_hh, fc1_w, fc1_b, fc2_w, fc2_b, outp);
}